// Round 6
// baseline (51.400 us; speedup 1.0000x reference)
//
#include <hip/hip_runtime.h>
#include <float.h>

typedef __attribute__((ext_vector_type(8))) short short8;
typedef __attribute__((ext_vector_type(4))) float f32x4;

#define SLOPE 0.2f
// leaky(t) = 0.6t + 0.4|t| for slope 0.2

__device__ __forceinline__ float leaky(float x) { return fmaxf(x, SLOPE * x); }

// f32 -> bf16 round-to-nearest-even
__device__ __forceinline__ unsigned short f2bf(float f) {
  unsigned u = __float_as_uint(f);
  return (unsigned short)((u + 0x7FFFu + ((u >> 16) & 1u)) >> 16);
}

// ---------------------------------------------------------------------------
// Kernel 1 "prep": blocks 0..255 = node MLPs (column-split: wave owns 16
// output cols for all 16 nodes -> weights read once per BLOCK, not per wave).
// Blocks 256..319 = edge transpose + bit-pack: ep[b][i][jt] u64, bit l =
// (edges[b][jt*64+l][i] != 0).
// ---------------------------------------------------------------------------
__global__ __launch_bounds__(256) void prep(
    const float* __restrict__ nodes, const int* __restrict__ edges,
    const float* __restrict__ self_w1, const float* __restrict__ self_b1,
    const float* __restrict__ self_w2, const float* __restrict__ self_b2,
    const float* __restrict__ nb_w1,   const float* __restrict__ nb_b1,
    const float* __restrict__ nb_w2,   const float* __restrict__ nb_b2,
    const float* __restrict__ comb_w1, const float* __restrict__ comb_b1,
    const float* __restrict__ comb_w2, const float* __restrict__ comb_b2,
    float* __restrict__ self_e, float* __restrict__ ss, float* __restrict__ sn,
    float* __restrict__ sP, float* __restrict__ sQ,
    unsigned short* __restrict__ nbT, unsigned long long* __restrict__ ep)
{
  __shared__ float x_sh[16][132];
  __shared__ float h_sh[16][68];
  __shared__ float e_sh[16][68];
  __shared__ float s_sh[16][68];
  __shared__ int   t_sh[64][65];

  const int tid = threadIdx.x, lane = tid & 63, wv = tid >> 6;

  if (blockIdx.x >= 256) {
    // ---------------- epack: 64 blocks, one 64-i x 512-j strip each --------
    const int blk = blockIdx.x - 256;       // 0..63
    const int b = blk >> 3, it = blk & 7;
    const int i0 = it * 64;
    for (int jt = 0; jt < 8; ++jt) {
      #pragma unroll
      for (int r = 0; r < 4; ++r) {
        const int idx = r * 256 + tid;      // 0..1023 int4s
        const int jr = idx >> 4, i4 = (idx & 15) * 4;
        *(int4*)&t_sh[jr][i4] =
            *(const int4*)&edges[((size_t)(b * 512 + jt * 64 + jr)) * 512 + i0 + i4];
      }
      __syncthreads();
      #pragma unroll
      for (int u = 0; u < 16; ++u) {
        const int ic = wv * 16 + u;
        const unsigned long long m = __ballot(t_sh[lane][ic] != 0);
        if (lane == 0) ep[((size_t)(b * 512 + i0 + ic)) * 8 + jt] = m;
      }
      __syncthreads();
    }
    return;
  }

  // ---------------- node MLPs: 16 nodes/block, column-split ----------------
  const int node0 = blockIdx.x * 16;
  const int bb = node0 >> 9;                // batch
  const int jloc = node0 & 511;             // batch-local node base

  {
    const float4* src = (const float4*)(nodes + (size_t)node0 * 128);
    #pragma unroll
    for (int r = 0; r < 2; ++r) {
      const int idx = r * 256 + tid;        // 0..511 float4s
      const int row = idx >> 5, c4 = (idx & 31) * 4;
      *(float4*)&x_sh[row][c4] = src[idx];
    }
  }
  __syncthreads();

  const int c0 = wv * 16 + (lane & 15);     // this lane's output column
  const int nd = lane >> 4;                 // node group (0..3)
  const float w2lane = comb_w2[lane];
  const float cb2 = comb_b2[0];

  for (int p = 0; p < 2; ++p) {
    const float* w1 = p ? nb_w1 : self_w1;
    const float* b1 = p ? nb_b1 : self_b1;
    const float* w2 = p ? nb_w2 : self_w2;
    const float* b2 = p ? nb_b2 : self_b2;
    const float* cw = comb_w1 + (p ? 64 * 64 : 0);

    // ---- layer 1: h = leaky(x @ w1 + b1) ----
    float acc[4];
    {
      const float bv = b1[c0];
      #pragma unroll
      for (int u = 0; u < 4; ++u) acc[u] = bv;
    }
    #pragma unroll 4
    for (int q = 0; q < 32; ++q) {
      const float w_0 = w1[(q * 4 + 0) * 64 + c0];
      const float w_1 = w1[(q * 4 + 1) * 64 + c0];
      const float w_2 = w1[(q * 4 + 2) * 64 + c0];
      const float w_3 = w1[(q * 4 + 3) * 64 + c0];
      #pragma unroll
      for (int u = 0; u < 4; ++u) {
        const float4 xv = *(const float4*)&x_sh[u * 4 + nd][q * 4];
        acc[u] += xv.x * w_0 + xv.y * w_1 + xv.z * w_2 + xv.w * w_3;
      }
    }
    #pragma unroll
    for (int u = 0; u < 4; ++u) h_sh[u * 4 + nd][c0] = leaky(acc[u]);
    __syncthreads();

    // ---- layer 2: e = h @ w2 + b2 ----
    {
      const float bv = b2[c0];
      #pragma unroll
      for (int u = 0; u < 4; ++u) acc[u] = bv;
    }
    #pragma unroll 4
    for (int q = 0; q < 16; ++q) {
      const float w_0 = w2[(q * 4 + 0) * 64 + c0];
      const float w_1 = w2[(q * 4 + 1) * 64 + c0];
      const float w_2 = w2[(q * 4 + 2) * 64 + c0];
      const float w_3 = w2[(q * 4 + 3) * 64 + c0];
      #pragma unroll
      for (int u = 0; u < 4; ++u) {
        const float4 hv = *(const float4*)&h_sh[u * 4 + nd][q * 4];
        acc[u] += hv.x * w_0 + hv.y * w_1 + hv.z * w_2 + hv.w * w_3;
      }
    }
    #pragma unroll
    for (int u = 0; u < 4; ++u) {
      e_sh[u * 4 + nd][c0] = acc[u];
      if (p == 0) self_e[(size_t)(node0 + u * 4 + nd) * 64 + c0] = acc[u];
    }
    __syncthreads();

    // ---- projection: s = e @ cw (+ comb_b1 for self path) ----
    {
      const float bv = p ? 0.f : comb_b1[c0];
      #pragma unroll
      for (int u = 0; u < 4; ++u) acc[u] = bv;
    }
    #pragma unroll 4
    for (int q = 0; q < 16; ++q) {
      const float w_0 = cw[(q * 4 + 0) * 64 + c0];
      const float w_1 = cw[(q * 4 + 1) * 64 + c0];
      const float w_2 = cw[(q * 4 + 2) * 64 + c0];
      const float w_3 = cw[(q * 4 + 3) * 64 + c0];
      #pragma unroll
      for (int u = 0; u < 4; ++u) {
        const float4 ev = *(const float4*)&e_sh[u * 4 + nd][q * 4];
        acc[u] += ev.x * w_0 + ev.y * w_1 + ev.z * w_2 + ev.w * w_3;
      }
    }
    {
      float* so = p ? sn : ss;
      #pragma unroll
      for (int u = 0; u < 4; ++u) {
        s_sh[u * 4 + nd][c0] = acc[u];
        so[(size_t)(node0 + u * 4 + nd) * 64 + c0] = acc[u];
      }
    }
    __syncthreads();

    // ---- rank-1 reduce: wave wv handles nodes wv*4+u ----
    #pragma unroll
    for (int u = 0; u < 4; ++u) {
      float r = s_sh[wv * 4 + u][lane] * w2lane;
      #pragma unroll
      for (int off = 32; off; off >>= 1) r += __shfl_xor(r, off);
      if (lane == 0) {
        float* po = p ? sQ : sP;
        po[node0 + wv * 4 + u] = 0.6f * r + (p ? 0.f : cb2);
      }
    }
    if (p == 1) {
      // nbT[b][h=lane][j]: wave wv packs its 4 consecutive nodes
      unsigned short v0 = f2bf(e_sh[wv * 4 + 0][lane]);
      unsigned short v1 = f2bf(e_sh[wv * 4 + 1][lane]);
      unsigned short v2 = f2bf(e_sh[wv * 4 + 2][lane]);
      unsigned short v3 = f2bf(e_sh[wv * 4 + 3][lane]);
      *(ushort4*)(nbT + ((size_t)(bb * 64 + lane)) * 512 + jloc + wv * 4) =
          make_ushort4(v0, v1, v2, v3);
    }
    __syncthreads();
  }
}

// ---------------------------------------------------------------------------
// Kernel B: 256 blocks (b = blk&7), 16 rows/block, 512 thr (8 waves).
// Wave wv owns rows {2wv, 2wv+1}: scores in registers, in-wave softmax,
// bf16 P -> LDS, MFMA aggregation (B straight from global, L2-hot).
// Edge masks come from pre-packed ep (wave-uniform u64 loads).
// ---------------------------------------------------------------------------
__global__ __launch_bounds__(512) void gat_attn(
    const unsigned long long* __restrict__ ep,
    const float* __restrict__ comb_w2,
    const float* __restrict__ self_e,
    const float* __restrict__ ss, const float* __restrict__ sn,
    const float* __restrict__ sP, const float* __restrict__ sQ,
    const unsigned short* __restrict__ nbT,
    float* __restrict__ out)
{
  __shared__ __align__(16) float sn_sh[2][64][68];          // 34.8 KB dbuf
  __shared__ __align__(16) unsigned short P_sh[16][520];    // 16.6 KB
  __shared__ __align__(16) float red_sh[4][64][4];          // 4 KB
  __shared__ float f_sh[16];

  const int tid = threadIdx.x, lane = tid & 63, wv = tid >> 6;
  const int b = blockIdx.x & 7, it = blockIdx.x >> 3;
  const int i0 = it * 16;
  const size_t nodeb = (size_t)b * 512;

  const int ra = wv * 2, rb = ra + 1;     // local rows (wave-owned)
  const int ia = i0 + ra, ib = ia + 1;    // batch-local rows

  // ---- edge masks from bit-packed ep (wave-uniform loads) + sQ ----
  unsigned em0 = 0, em1 = 0;
  float sQv[8];
  {
    const unsigned long long* e0 = ep + (nodeb + ia) * 8;
    const unsigned long long* e1 = ep + (nodeb + ib) * 8;
    #pragma unroll
    for (int jt = 0; jt < 8; ++jt) {
      em0 |= (unsigned)((e0[jt] >> lane) & 1ull) << jt;
      em1 |= (unsigned)((e1[jt] >> lane) & 1ull) << jt;
      sQv[jt] = sQ[nodeb + jt * 64 + lane];
    }
  }
  {
    const int d0 = ia - lane;             // self-loop: jt*64+lane == ia
    if (d0 >= 0 && (d0 & 63) == 0) em0 &= ~(1u << (d0 >> 6));
    const int d1 = ib - lane;
    if (d1 >= 0 && (d1 & 63) == 0) em1 &= ~(1u << (d1 >> 6));
  }

  // ---- hoist: w2p (0.4*w2), ss rows, sP scalars -> registers ----
  float4 w2p[16], sa0[16], sa1[16];
  {
    const float4* w2v = (const float4*)comb_w2;
    const float4* s0 = (const float4*)(ss + (nodeb + ia) * 64);
    const float4* s1 = (const float4*)(ss + (nodeb + ib) * 64);
    #pragma unroll
    for (int q = 0; q < 16; ++q) {
      float4 w = w2v[q];
      w2p[q] = make_float4(0.4f * w.x, 0.4f * w.y, 0.4f * w.z, 0.4f * w.w);
      sa0[q] = s0[q];
      sa1[q] = s1[q];
    }
  }
  const float sPa = sP[nodeb + ia], sPb = sP[nodeb + ib];

  // ---- phase 1: scores, double-buffered sn staging (1 barrier/tile) ----
  const int str = tid >> 4, stc = (tid & 15) * 4;
  const int str2 = (tid + 512) >> 4, stc2 = ((tid + 512) & 15) * 4;
  float4 st0, st1;
  {
    const float4* src = (const float4*)(sn + nodeb * 64);
    st0 = src[tid];
    st1 = src[tid + 512];
  }

  float msc0[8], msc1[8];
  int cur = 0;
  for (int jt = 0; jt < 8; ++jt) {
    *(float4*)&sn_sh[cur][str][stc] = st0;
    *(float4*)&sn_sh[cur][str2][stc2] = st1;
    if (jt < 7) {
      const float4* src = (const float4*)(sn + (nodeb + (jt + 1) * 64) * 64);
      st0 = src[tid];
      st1 = src[tid + 512];
    }
    __syncthreads();

    float acc0 = 0.f, acc1 = 0.f;
    #pragma unroll
    for (int q = 0; q < 16; ++q) {
      float4 v = *(const float4*)&sn_sh[cur][lane][q * 4];
      float4 w = w2p[q];
      float4 A = sa0[q];
      float4 Bv = sa1[q];
      acc0 += w.x * fabsf(A.x + v.x) + w.y * fabsf(A.y + v.y)
            + w.z * fabsf(A.z + v.z) + w.w * fabsf(A.w + v.w);
      acc1 += w.x * fabsf(Bv.x + v.x) + w.y * fabsf(Bv.y + v.y)
            + w.z * fabsf(Bv.z + v.z) + w.w * fabsf(Bv.w + v.w);
    }
    msc0[jt] = ((em0 >> jt) & 1u) ? acc0 + sPa + sQv[jt] : -FLT_MAX;
    msc1[jt] = ((em1 >> jt) & 1u) ? acc1 + sPb + sQv[jt] : -FLT_MAX;
    cur ^= 1;
  }

  // ---- phase 2: in-wave softmax (rows wholly owned by this wave) ----
  float m0 = msc0[0], m1 = msc1[0];
  #pragma unroll
  for (int jt = 1; jt < 8; ++jt) {
    m0 = fmaxf(m0, msc0[jt]);
    m1 = fmaxf(m1, msc1[jt]);
  }
  #pragma unroll
  for (int off = 32; off; off >>= 1) {
    m0 = fmaxf(m0, __shfl_xor(m0, off));
    m1 = fmaxf(m1, __shfl_xor(m1, off));
  }

  float s0 = 0.f, s1 = 0.f;
  #pragma unroll
  for (int jt = 0; jt < 8; ++jt) {
    const float e0 = __expf(msc0[jt] - m0);
    const float e1 = __expf(msc1[jt] - m1);
    P_sh[ra][jt * 64 + lane] = f2bf(e0);
    P_sh[rb][jt * 64 + lane] = f2bf(e1);
    s0 += e0;
    s1 += e1;
  }
  #pragma unroll
  for (int off = 32; off; off >>= 1) {
    s0 += __shfl_xor(s0, off);
    s1 += __shfl_xor(s1, off);
  }
  if (lane == 0) {
    f_sh[ra] = (m0 > -1e37f) ? 1.0f / s0 : 0.0f;
    f_sh[rb] = (m1 > -1e37f) ? 1.0f / s1 : 0.0f;
  }
  __syncthreads();                        // P_sh + f_sh visible to all waves

  // ---- phase 3: MFMA aggregation (A from LDS, B straight from global) ----
  const int nt = wv & 3, kh = wv >> 2;
  const int arow = lane & 15, agrp = lane >> 4;
  const int bcol = nt * 16 + (lane & 15);
  const unsigned short* nbrow = nbT + ((size_t)(b * 64 + bcol)) * 512;

  f32x4 C = {0.f, 0.f, 0.f, 0.f};
  #pragma unroll
  for (int ks = 0; ks < 8; ++ks) {
    const int jb = kh * 256 + ks * 32 + agrp * 8;
    short8 afr = *(const short8*)&P_sh[arow][jb];
    short8 bfr = *(const short8*)(nbrow + jb);
    C = __builtin_amdgcn_mfma_f32_16x16x32_bf16(afr, bfr, C, 0, 0, 0);
  }
  if (kh == 1) *(f32x4*)&red_sh[wv - 4][lane][0] = C;
  __syncthreads();
  if (kh == 0) {
    f32x4 P = *(const f32x4*)&red_sh[wv][lane][0];
    #pragma unroll
    for (int r = 0; r < 4; ++r) {
      const int rg = agrp * 4 + r;        // C/D: row = (lane>>4)*4 + reg
      const float f = f_sh[rg];
      const size_t adr = (nodeb + i0 + rg) * 64 + bcol;
      const float val = (C[r] + P[r]) * f + self_e[adr];
      out[adr] = (f > 0.f) ? val : 0.f;
    }
  }
}

// ---------------------------------------------------------------------------
extern "C" void kernel_launch(void* const* d_in, const int* in_sizes, int n_in,
                              void* d_out, int out_size, void* d_ws, size_t ws_size,
                              hipStream_t stream) {
  const float* nodes   = (const float*)d_in[0];
  const int*   edges   = (const int*)  d_in[1];
  const float* self_w1 = (const float*)d_in[2];
  const float* self_b1 = (const float*)d_in[3];
  const float* self_w2 = (const float*)d_in[4];
  const float* self_b2 = (const float*)d_in[5];
  const float* nb_w1   = (const float*)d_in[6];
  const float* nb_b1   = (const float*)d_in[7];
  const float* nb_w2   = (const float*)d_in[8];
  const float* nb_b2   = (const float*)d_in[9];
  const float* comb_w1 = (const float*)d_in[10];
  const float* comb_b1 = (const float*)d_in[11];
  const float* comb_w2 = (const float*)d_in[12];
  const float* comb_b2 = (const float*)d_in[13];

  float* ws     = (float*)d_ws;
  float* self_e = ws;                       // 262144 floats
  float* ss     = ws + 262144;              // 262144
  float* sn     = ws + 524288;              // 262144 (row-major [b][j][k])
  float* sP     = ws + 786432;              // 4096
  float* sQ     = ws + 790528;              // 4096
  unsigned short* nbT = (unsigned short*)(ws + 794624);        // 524288 B
  unsigned long long* ep = (unsigned long long*)(ws + 925696); // 262144 B

  prep<<<320, 256, 0, stream>>>(
      nodes, edges, self_w1, self_b1, self_w2, self_b2,
      nb_w1, nb_b1, nb_w2, nb_b2, comb_w1, comb_b1, comb_w2, comb_b2,
      self_e, ss, sn, sP, sQ, nbT, ep);

  gat_attn<<<256, 512, 0, stream>>>(
      ep, comb_w2, self_e, ss, sn, sP, sQ, nbT, (float*)d_out);
}

// Round 7
// 42.265 us; speedup vs baseline: 1.2161x; 1.2161x over previous
//
#include <hip/hip_runtime.h>
#include <float.h>

typedef __attribute__((ext_vector_type(8))) short short8;
typedef __attribute__((ext_vector_type(4))) float f32x4;

#define SLOPE 0.2f
// leaky(t) = 0.6t + 0.4|t| for slope 0.2

__device__ __forceinline__ float leaky(float x) { return fmaxf(x, SLOPE * x); }

// f32 -> bf16 round-to-nearest-even
__device__ __forceinline__ unsigned short f2bf(float f) {
  unsigned u = __float_as_uint(f);
  return (unsigned short)((u + 0x7FFFu + ((u >> 16) & 1u)) >> 16);
}

// ---------------------------------------------------------------------------
// Kernel 1 "prep":
//  blocks 0..511  = node MLPs (R5 row-split: lane = output col, coalesced
//                   256B wave-loads of weights; 8 nodes/block, 2/wave)
//  blocks 512..575 = edge transpose + bit-pack: ep[b][i][jt] u64, bit l =
//                   (edges[b][jt*64+l][i] != 0)  -- runs concurrently.
// ---------------------------------------------------------------------------
__global__ __launch_bounds__(256) void prep(
    const float* __restrict__ nodes, const int* __restrict__ edges,
    const float* __restrict__ self_w1, const float* __restrict__ self_b1,
    const float* __restrict__ self_w2, const float* __restrict__ self_b2,
    const float* __restrict__ nb_w1,   const float* __restrict__ nb_b1,
    const float* __restrict__ nb_w2,   const float* __restrict__ nb_b2,
    const float* __restrict__ comb_w1, const float* __restrict__ comb_b1,
    const float* __restrict__ comb_w2, const float* __restrict__ comb_b2,
    float* __restrict__ self_e, float* __restrict__ ss, float* __restrict__ sn,
    float* __restrict__ sP, float* __restrict__ sQ,
    unsigned short* __restrict__ nbT, unsigned long long* __restrict__ ep)
{
  __shared__ float x_sh[8][128];
  __shared__ float h_sh[8][64];
  __shared__ float e_sh[8][64];
  __shared__ int   t_sh[64][65];

  const int tid = threadIdx.x, lane = tid & 63, wv = tid >> 6;

  if (blockIdx.x >= 512) {
    // ---------------- epack: 64 blocks, one 64-i x 512-j strip each --------
    const int blk = blockIdx.x - 512;       // 0..63
    const int b = blk >> 3, it = blk & 7;
    const int i0 = it * 64;
    for (int jt = 0; jt < 8; ++jt) {
      #pragma unroll
      for (int r = 0; r < 4; ++r) {
        const int idx = r * 256 + tid;      // 0..1023 int4s
        const int jr = idx >> 4, i4 = (idx & 15) * 4;
        *(int4*)&t_sh[jr][i4] =
            *(const int4*)&edges[((size_t)(b * 512 + jt * 64 + jr)) * 512 + i0 + i4];
      }
      __syncthreads();
      #pragma unroll
      for (int u = 0; u < 16; ++u) {
        const int ic = wv * 16 + u;
        const unsigned long long m = __ballot(t_sh[lane][ic] != 0);
        if (lane == 0) ep[((size_t)(b * 512 + i0 + ic)) * 8 + jt] = m;
      }
      __syncthreads();
    }
    return;
  }

  // ---------------- node MLPs: 8 nodes/block, row-split (R5) ---------------
  const int node0 = blockIdx.x * 8;
  const int bb = node0 >> 9;          // batch
  const int jloc = node0 & 511;       // batch-local node base

  ((float4*)&x_sh[0][0])[tid] = ((const float4*)(nodes + (size_t)node0 * 128))[tid];
  __syncthreads();

  const int la = wv * 2, lb = la + 1;
  const float w2lane = comb_w2[lane];
  const float cb2 = comb_b2[0];
  const float cb1 = comb_b1[lane];

  for (int p = 0; p < 2; ++p) {
    const float* w1 = p ? nb_w1 : self_w1;
    const float* b1 = p ? nb_b1 : self_b1;
    const float* w2 = p ? nb_w2 : self_w2;
    const float* b2 = p ? nb_b2 : self_b2;
    const float* cw = comb_w1 + (p ? 64 * 64 : 0);

    // ---- layer 1 ----
    float a0 = 0.f, a1 = 0.f, c0 = 0.f, c1 = 0.f;
    #pragma unroll 4
    for (int q = 0; q < 32; ++q) {
      float4 xa = *(const float4*)&x_sh[la][q * 4];
      float4 xb = *(const float4*)&x_sh[lb][q * 4];
      float w_0 = w1[(q * 4 + 0) * 64 + lane];
      float w_1 = w1[(q * 4 + 1) * 64 + lane];
      float w_2 = w1[(q * 4 + 2) * 64 + lane];
      float w_3 = w1[(q * 4 + 3) * 64 + lane];
      a0 += xa.x * w_0; a1 += xa.y * w_1; a0 += xa.z * w_2; a1 += xa.w * w_3;
      c0 += xb.x * w_0; c1 += xb.y * w_1; c0 += xb.z * w_2; c1 += xb.w * w_3;
    }
    {
      float bv = b1[lane];
      h_sh[la][lane] = leaky(a0 + a1 + bv);
      h_sh[lb][lane] = leaky(c0 + c1 + bv);
    }
    __syncthreads();

    // ---- layer 2 ----
    a0 = a1 = c0 = c1 = 0.f;
    #pragma unroll 4
    for (int q = 0; q < 16; ++q) {
      float4 ha = *(const float4*)&h_sh[la][q * 4];
      float4 hb = *(const float4*)&h_sh[lb][q * 4];
      float w_0 = w2[(q * 4 + 0) * 64 + lane];
      float w_1 = w2[(q * 4 + 1) * 64 + lane];
      float w_2 = w2[(q * 4 + 2) * 64 + lane];
      float w_3 = w2[(q * 4 + 3) * 64 + lane];
      a0 += ha.x * w_0; a1 += ha.y * w_1; a0 += ha.z * w_2; a1 += ha.w * w_3;
      c0 += hb.x * w_0; c1 += hb.y * w_1; c0 += hb.z * w_2; c1 += hb.w * w_3;
    }
    float e_a, e_b;
    {
      float bv = b2[lane];
      e_a = a0 + a1 + bv;
      e_b = c0 + c1 + bv;
    }
    e_sh[la][lane] = e_a;
    e_sh[lb][lane] = e_b;
    if (p == 0) {
      self_e[(size_t)(node0 + la) * 64 + lane] = e_a;
      self_e[(size_t)(node0 + lb) * 64 + lane] = e_b;
    }
    __syncthreads();

    // ---- projection ----
    a0 = a1 = c0 = c1 = 0.f;
    #pragma unroll 4
    for (int q = 0; q < 16; ++q) {
      float4 ea = *(const float4*)&e_sh[la][q * 4];
      float4 eb = *(const float4*)&e_sh[lb][q * 4];
      float w_0 = cw[(q * 4 + 0) * 64 + lane];
      float w_1 = cw[(q * 4 + 1) * 64 + lane];
      float w_2 = cw[(q * 4 + 2) * 64 + lane];
      float w_3 = cw[(q * 4 + 3) * 64 + lane];
      a0 += ea.x * w_0; a1 += ea.y * w_1; a0 += ea.z * w_2; a1 += ea.w * w_3;
      c0 += eb.x * w_0; c1 += eb.y * w_1; c0 += eb.z * w_2; c1 += eb.w * w_3;
    }
    float s_a = a0 + a1 + (p ? 0.f : cb1);
    float s_b = c0 + c1 + (p ? 0.f : cb1);
    {
      float* so = p ? sn : ss;
      so[(size_t)(node0 + la) * 64 + lane] = s_a;
      so[(size_t)(node0 + lb) * 64 + lane] = s_b;
    }
    float ra = w2lane * s_a, rb = w2lane * s_b;
    #pragma unroll
    for (int off = 32; off; off >>= 1) {
      ra += __shfl_xor(ra, off);
      rb += __shfl_xor(rb, off);
    }
    if (lane == 0) {
      float* po = p ? sQ : sP;
      float add = p ? 0.f : cb2;
      po[node0 + la] = 0.6f * ra + add;
      po[node0 + lb] = 0.6f * rb + add;
    }

    if (p == 1) {
      // nbT[b][h=lane][j]
      unsigned pack = (unsigned)f2bf(e_a) | ((unsigned)f2bf(e_b) << 16);
      *(unsigned*)(nbT + ((size_t)(bb * 64 + lane) * 512 + jloc + la)) = pack;
    }
    __syncthreads();
  }
}

// ---------------------------------------------------------------------------
// Kernel B: 256 blocks (b = blk&7), 16 rows/block, 512 thr (8 waves).
// Wave wv owns rows {2wv, 2wv+1}: scores in registers, in-wave softmax,
// bf16 P -> LDS, MFMA aggregation (B straight from global, L2-hot).
// Edge masks come from pre-packed ep (wave-uniform u64 loads).
// ---------------------------------------------------------------------------
__global__ __launch_bounds__(512) void gat_attn(
    const unsigned long long* __restrict__ ep,
    const float* __restrict__ comb_w2,
    const float* __restrict__ self_e,
    const float* __restrict__ ss, const float* __restrict__ sn,
    const float* __restrict__ sP, const float* __restrict__ sQ,
    const unsigned short* __restrict__ nbT,
    float* __restrict__ out)
{
  __shared__ __align__(16) float sn_sh[2][64][68];          // 34.8 KB dbuf
  __shared__ __align__(16) unsigned short P_sh[16][520];    // 16.6 KB
  __shared__ __align__(16) float red_sh[4][64][4];          // 4 KB
  __shared__ float f_sh[16];

  const int tid = threadIdx.x, lane = tid & 63, wv = tid >> 6;
  const int b = blockIdx.x & 7, it = blockIdx.x >> 3;
  const int i0 = it * 16;
  const size_t nodeb = (size_t)b * 512;

  const int ra = wv * 2, rb = ra + 1;     // local rows (wave-owned)
  const int ia = i0 + ra, ib = ia + 1;    // batch-local rows

  // ---- edge masks from bit-packed ep (wave-uniform loads) + sQ ----
  unsigned em0 = 0, em1 = 0;
  float sQv[8];
  {
    const unsigned long long* e0 = ep + (nodeb + ia) * 8;
    const unsigned long long* e1 = ep + (nodeb + ib) * 8;
    #pragma unroll
    for (int jt = 0; jt < 8; ++jt) {
      em0 |= (unsigned)((e0[jt] >> lane) & 1ull) << jt;
      em1 |= (unsigned)((e1[jt] >> lane) & 1ull) << jt;
      sQv[jt] = sQ[nodeb + jt * 64 + lane];
    }
  }
  {
    const int d0 = ia - lane;             // self-loop: jt*64+lane == ia
    if (d0 >= 0 && (d0 & 63) == 0) em0 &= ~(1u << (d0 >> 6));
    const int d1 = ib - lane;
    if (d1 >= 0 && (d1 & 63) == 0) em1 &= ~(1u << (d1 >> 6));
  }

  // ---- hoist: w2p (0.4*w2), ss rows, sP scalars -> registers ----
  float4 w2p[16], sa0[16], sa1[16];
  {
    const float4* w2v = (const float4*)comb_w2;
    const float4* s0 = (const float4*)(ss + (nodeb + ia) * 64);
    const float4* s1 = (const float4*)(ss + (nodeb + ib) * 64);
    #pragma unroll
    for (int q = 0; q < 16; ++q) {
      float4 w = w2v[q];
      w2p[q] = make_float4(0.4f * w.x, 0.4f * w.y, 0.4f * w.z, 0.4f * w.w);
      sa0[q] = s0[q];
      sa1[q] = s1[q];
    }
  }
  const float sPa = sP[nodeb + ia], sPb = sP[nodeb + ib];

  // ---- phase 1: scores, double-buffered sn staging (1 barrier/tile) ----
  const int str = tid >> 4, stc = (tid & 15) * 4;
  const int str2 = (tid + 512) >> 4, stc2 = ((tid + 512) & 15) * 4;
  float4 st0, st1;
  {
    const float4* src = (const float4*)(sn + nodeb * 64);
    st0 = src[tid];
    st1 = src[tid + 512];
  }

  float msc0[8], msc1[8];
  int cur = 0;
  for (int jt = 0; jt < 8; ++jt) {
    *(float4*)&sn_sh[cur][str][stc] = st0;
    *(float4*)&sn_sh[cur][str2][stc2] = st1;
    if (jt < 7) {
      const float4* src = (const float4*)(sn + (nodeb + (jt + 1) * 64) * 64);
      st0 = src[tid];
      st1 = src[tid + 512];
    }
    __syncthreads();

    float acc0 = 0.f, acc1 = 0.f;
    #pragma unroll
    for (int q = 0; q < 16; ++q) {
      float4 v = *(const float4*)&sn_sh[cur][lane][q * 4];
      float4 w = w2p[q];
      float4 A = sa0[q];
      float4 Bv = sa1[q];
      acc0 += w.x * fabsf(A.x + v.x) + w.y * fabsf(A.y + v.y)
            + w.z * fabsf(A.z + v.z) + w.w * fabsf(A.w + v.w);
      acc1 += w.x * fabsf(Bv.x + v.x) + w.y * fabsf(Bv.y + v.y)
            + w.z * fabsf(Bv.z + v.z) + w.w * fabsf(Bv.w + v.w);
    }
    msc0[jt] = ((em0 >> jt) & 1u) ? acc0 + sPa + sQv[jt] : -FLT_MAX;
    msc1[jt] = ((em1 >> jt) & 1u) ? acc1 + sPb + sQv[jt] : -FLT_MAX;
    cur ^= 1;
  }

  // ---- phase 2: in-wave softmax (rows wholly owned by this wave) ----
  float m0 = msc0[0], m1 = msc1[0];
  #pragma unroll
  for (int jt = 1; jt < 8; ++jt) {
    m0 = fmaxf(m0, msc0[jt]);
    m1 = fmaxf(m1, msc1[jt]);
  }
  #pragma unroll
  for (int off = 32; off; off >>= 1) {
    m0 = fmaxf(m0, __shfl_xor(m0, off));
    m1 = fmaxf(m1, __shfl_xor(m1, off));
  }

  float s0 = 0.f, s1 = 0.f;
  #pragma unroll
  for (int jt = 0; jt < 8; ++jt) {
    const float e0 = __expf(msc0[jt] - m0);
    const float e1 = __expf(msc1[jt] - m1);
    P_sh[ra][jt * 64 + lane] = f2bf(e0);
    P_sh[rb][jt * 64 + lane] = f2bf(e1);
    s0 += e0;
    s1 += e1;
  }
  #pragma unroll
  for (int off = 32; off; off >>= 1) {
    s0 += __shfl_xor(s0, off);
    s1 += __shfl_xor(s1, off);
  }
  if (lane == 0) {
    f_sh[ra] = (m0 > -1e37f) ? 1.0f / s0 : 0.0f;
    f_sh[rb] = (m1 > -1e37f) ? 1.0f / s1 : 0.0f;
  }
  __syncthreads();                        // P_sh + f_sh visible to all waves

  // ---- phase 3: MFMA aggregation (A from LDS, B straight from global) ----
  const int nt = wv & 3, kh = wv >> 2;
  const int arow = lane & 15, agrp = lane >> 4;
  const int bcol = nt * 16 + (lane & 15);
  const unsigned short* nbrow = nbT + ((size_t)(b * 64 + bcol)) * 512;

  f32x4 C = {0.f, 0.f, 0.f, 0.f};
  #pragma unroll
  for (int ks = 0; ks < 8; ++ks) {
    const int jb = kh * 256 + ks * 32 + agrp * 8;
    short8 afr = *(const short8*)&P_sh[arow][jb];
    short8 bfr = *(const short8*)(nbrow + jb);
    C = __builtin_amdgcn_mfma_f32_16x16x32_bf16(afr, bfr, C, 0, 0, 0);
  }
  if (kh == 1) *(f32x4*)&red_sh[wv - 4][lane][0] = C;
  __syncthreads();
  if (kh == 0) {
    f32x4 P = *(const f32x4*)&red_sh[wv][lane][0];
    #pragma unroll
    for (int r = 0; r < 4; ++r) {
      const int rg = agrp * 4 + r;        // C/D: row = (lane>>4)*4 + reg
      const float f = f_sh[rg];
      const size_t adr = (nodeb + i0 + rg) * 64 + bcol;
      const float val = (C[r] + P[r]) * f + self_e[adr];
      out[adr] = (f > 0.f) ? val : 0.f;
    }
  }
}

// ---------------------------------------------------------------------------
extern "C" void kernel_launch(void* const* d_in, const int* in_sizes, int n_in,
                              void* d_out, int out_size, void* d_ws, size_t ws_size,
                              hipStream_t stream) {
  const float* nodes   = (const float*)d_in[0];
  const int*   edges   = (const int*)  d_in[1];
  const float* self_w1 = (const float*)d_in[2];
  const float* self_b1 = (const float*)d_in[3];
  const float* self_w2 = (const float*)d_in[4];
  const float* self_b2 = (const float*)d_in[5];
  const float* nb_w1   = (const float*)d_in[6];
  const float* nb_b1   = (const float*)d_in[7];
  const float* nb_w2   = (const float*)d_in[8];
  const float* nb_b2   = (const float*)d_in[9];
  const float* comb_w1 = (const float*)d_in[10];
  const float* comb_b1 = (const float*)d_in[11];
  const float* comb_w2 = (const float*)d_in[12];
  const float* comb_b2 = (const float*)d_in[13];

  float* ws     = (float*)d_ws;
  float* self_e = ws;                       // 262144 floats
  float* ss     = ws + 262144;              // 262144
  float* sn     = ws + 524288;              // 262144 (row-major [b][j][k])
  float* sP     = ws + 786432;              // 4096
  float* sQ     = ws + 790528;              // 4096
  unsigned short* nbT = (unsigned short*)(ws + 794624);        // 524288 B
  unsigned long long* ep = (unsigned long long*)(ws + 925696); // 262144 B

  prep<<<576, 256, 0, stream>>>(
      nodes, edges, self_w1, self_b1, self_w2, self_b2,
      nb_w1, nb_b1, nb_w2, nb_b2, comb_w1, comb_b1, comb_w2, comb_b2,
      self_e, ss, sn, sP, sQ, nbT, ep);

  gat_attn<<<256, 512, 0, stream>>>(
      ep, comb_w2, self_e, ss, sn, sP, sQ, nbT, (float*)d_out);
}